// Round 1
// baseline (816.919 us; speedup 1.0000x reference)
//
#include <hip/hip_runtime.h>

#define NSP 2304   // 48*48 spatial
#define NB  4      // batch

// ---------------------------------------------------------------------------
// GEMM: Y[b] = W (MxK, row-major) * X[b] (KxN, row-major)  (+ optional bias[M])
// 64x64 tile, K-tile 16, 256 threads, 4x4 per thread.
// ---------------------------------------------------------------------------
__global__ __launch_bounds__(256) void gemm_f32(
    const float* __restrict__ W, const float* __restrict__ X,
    float* __restrict__ Y, const float* __restrict__ bias,
    int M, int N, int K) {
  const int b = blockIdx.z;
  X += (size_t)b * K * N;
  Y += (size_t)b * M * N;

  __shared__ float As[16][64];   // [k][m]
  __shared__ float Bs[16][64];   // [k][n]

  const int t  = threadIdx.x;
  const int tx = t & 15;        // 16 col-groups
  const int ty = t >> 4;        // 16 row-groups
  const int row0 = blockIdx.y * 64;
  const int col0 = blockIdx.x * 64;

  float acc[4][4];
#pragma unroll
  for (int i = 0; i < 4; ++i)
#pragma unroll
    for (int j = 0; j < 4; ++j) acc[i][j] = 0.0f;

  for (int k0 = 0; k0 < K; k0 += 16) {
    // A tile: 64(m) x 16(k); thread reads consecutive k for coalescing-ish
#pragma unroll
    for (int l = t; l < 64 * 16; l += 256) {
      int kk = l & 15, mm = l >> 4;
      As[kk][mm] = W[(size_t)(row0 + mm) * K + (k0 + kk)];
    }
    // B tile: 16(k) x 64(n); consecutive n => coalesced
#pragma unroll
    for (int l = t; l < 16 * 64; l += 256) {
      int nn = l & 63, kk = l >> 6;
      Bs[kk][nn] = X[(size_t)(k0 + kk) * N + (col0 + nn)];
    }
    __syncthreads();
#pragma unroll
    for (int kk = 0; kk < 16; ++kk) {
      float4 a  = *(const float4*)&As[kk][ty * 4];
      float4 bb = *(const float4*)&Bs[kk][tx * 4];
      float av[4] = {a.x, a.y, a.z, a.w};
      float bv[4] = {bb.x, bb.y, bb.z, bb.w};
#pragma unroll
      for (int i = 0; i < 4; ++i)
#pragma unroll
        for (int j = 0; j < 4; ++j) acc[i][j] = fmaf(av[i], bv[j], acc[i][j]);
    }
    __syncthreads();
  }

#pragma unroll
  for (int i = 0; i < 4; ++i) {
    int mm = row0 + ty * 4 + i;
    float bv = bias ? bias[mm] : 0.0f;
#pragma unroll
    for (int j = 0; j < 4; ++j)
      Y[(size_t)mm * N + col0 + tx * 4 + j] = acc[i][j] + bv;
  }
}

// ---------------------------------------------------------------------------
// Flash-style attention.
// qkv layout: [B][3*256][n]; q at ch h*32+d, k at 256+h*32+d, v at 512+h*32+d.
// One block = (b, h, tile of 64 queries). 256 threads.
// Thread t: query row qi = t>>2 (0..63), group g = t&3.
//   S phase : computes S[qi][g*16 .. g*16+15]
//   PV phase: owns d in {g + 4*dd, dd=0..7}  (stride-4 => conflict-free Vs b128)
// ---------------------------------------------------------------------------
__global__ __launch_bounds__(256) void attn_kernel(
    const float* __restrict__ qkv, float* __restrict__ out) {
  const int n  = NSP;
  const int it = blockIdx.x;
  const int h  = blockIdx.y;
  const int b  = blockIdx.z;
  const float scale = 0.17677669529663687f;  // 32^-0.5

  const float* qb = qkv + ((size_t)b * 768 + h * 32) * n;
  const float* kb = qb + (size_t)256 * n;
  const float* vb = qb + (size_t)512 * n;
  float* ob = out + ((size_t)b * 256 + h * 32) * n;

  __shared__ float Qs[32][64];
  __shared__ float Ks[32][64];
  __shared__ float Vs[32][68];
  __shared__ float Ps[64][68];
  __shared__ float redm[64][4];
  __shared__ float redl[64][4];

  const int t  = threadIdx.x;
  const int qi = t >> 2;
  const int g  = t & 3;
  const int i0 = it * 64;

  // Q tile: [d][i]
#pragma unroll
  for (int l = t; l < 32 * 64; l += 256) {
    int d = l >> 6, i = l & 63;
    Qs[d][i] = qb[(size_t)d * n + i0 + i];
  }

  float m = -1e30f, lsum = 0.0f;
  float acc[8];
#pragma unroll
  for (int dd = 0; dd < 8; ++dd) acc[dd] = 0.0f;

  for (int j0 = 0; j0 < n; j0 += 64) {
    __syncthreads();  // previous iter's Ps/Ks/Vs reads complete
#pragma unroll
    for (int l = t; l < 32 * 64; l += 256) {
      int d = l >> 6, j = l & 63;
      Ks[d][j] = kb[(size_t)d * n + j0 + j];
      Vs[d][j] = vb[(size_t)d * n + j0 + j];
    }
    __syncthreads();

    // ---- S = Q^T K for this thread's 16 columns ----
    float s[16];
#pragma unroll
    for (int jj = 0; jj < 16; ++jj) s[jj] = 0.0f;
#pragma unroll 8
    for (int d = 0; d < 32; ++d) {
      float qv = Qs[d][qi];
      const float4* kr = (const float4*)&Ks[d][g * 16];
#pragma unroll
      for (int jj4 = 0; jj4 < 4; ++jj4) {
        float4 kv = kr[jj4];
        s[jj4 * 4 + 0] = fmaf(qv, kv.x, s[jj4 * 4 + 0]);
        s[jj4 * 4 + 1] = fmaf(qv, kv.y, s[jj4 * 4 + 1]);
        s[jj4 * 4 + 2] = fmaf(qv, kv.z, s[jj4 * 4 + 2]);
        s[jj4 * 4 + 3] = fmaf(qv, kv.w, s[jj4 * 4 + 3]);
      }
    }

    // ---- online softmax ----
    float pmax = -1e30f;
#pragma unroll
    for (int jj = 0; jj < 16; ++jj) {
      s[jj] *= scale;
      pmax = fmaxf(pmax, s[jj]);
    }
    redm[qi][g] = pmax;
    __syncthreads();
    pmax = fmaxf(fmaxf(redm[qi][0], redm[qi][1]),
                 fmaxf(redm[qi][2], redm[qi][3]));
    float mnew = fmaxf(m, pmax);
    float corr = __expf(m - mnew);
    float psum = 0.0f;
#pragma unroll
    for (int jj = 0; jj < 16; ++jj) {
      float p = __expf(s[jj] - mnew);
      psum += p;
      Ps[qi][g * 16 + jj] = p;
    }
    redl[qi][g] = psum;
    __syncthreads();  // Ps + redl visible
    psum = redl[qi][0] + redl[qi][1] + redl[qi][2] + redl[qi][3];
    lsum = lsum * corr + psum;
    m = mnew;

    // ---- PV accumulate: acc[dd] for d = g + 4*dd ----
#pragma unroll
    for (int dd = 0; dd < 8; ++dd) acc[dd] *= corr;
#pragma unroll 4
    for (int j4 = 0; j4 < 16; ++j4) {
      float4 p = *(const float4*)&Ps[qi][j4 * 4];
      float pv[4] = {p.x, p.y, p.z, p.w};
#pragma unroll
      for (int dd = 0; dd < 8; ++dd) {
        float4 v = *(const float4*)&Vs[g + 4 * dd][j4 * 4];
        acc[dd] = fmaf(pv[0], v.x, acc[dd]);
        acc[dd] = fmaf(pv[1], v.y, acc[dd]);
        acc[dd] = fmaf(pv[2], v.z, acc[dd]);
        acc[dd] = fmaf(pv[3], v.w, acc[dd]);
      }
    }
  }

  float inv = 1.0f / lsum;
#pragma unroll
  for (int dd = 0; dd < 8; ++dd)
    ob[(size_t)(g + 4 * dd) * n + i0 + qi] = acc[dd] * inv;
}

// ---------------------------------------------------------------------------
extern "C" void kernel_launch(void* const* d_in, const int* in_sizes, int n_in,
                              void* d_out, int out_size, void* d_ws, size_t ws_size,
                              hipStream_t stream) {
  const float* x     = (const float*)d_in[0];  // [4][256][48][48]
  const float* w_qkv = (const float*)d_in[1];  // [768][256]
  const float* w_out = (const float*)d_in[2];  // [256][256]
  const float* b_out = (const float*)d_in[3];  // [256]
  float* out = (float*)d_out;                  // [4][256][48][48]

  float* qkv   = (float*)d_ws;                       // [4][768][2304]
  float* attno = qkv + (size_t)NB * 768 * NSP;       // [4][256][2304]

  dim3 blk(256);
  // QKV projection: per batch W_qkv(768x256) * X(256x2304)
  gemm_f32<<<dim3(NSP / 64, 768 / 64, NB), blk, 0, stream>>>(
      w_qkv, x, qkv, nullptr, 768, NSP, 256);
  // Attention
  attn_kernel<<<dim3(NSP / 64, 8, NB), blk, 0, stream>>>(qkv, attno);
  // Output projection + bias: per batch W_out(256x256) * attno(256x2304)
  gemm_f32<<<dim3(NSP / 64, 256 / 64, NB), blk, 0, stream>>>(
      w_out, attno, out, b_out, 256, NSP, 256);
}

// Round 2
// 287.339 us; speedup vs baseline: 2.8430x; 2.8430x over previous
//
#include <hip/hip_runtime.h>
#include <hip/hip_bf16.h>
#include <type_traits>

#define NSP 2304   // 48*48 spatial
#define NB  4      // batch

typedef __attribute__((ext_vector_type(8))) short short8;
typedef __attribute__((ext_vector_type(4))) float f32x4;

static __device__ inline unsigned short f2bf(float f) {
  __hip_bfloat16 h = __float2bfloat16(f);
  return __builtin_bit_cast(unsigned short, h);
}

// ---------------------------------------------------------------------------
// GEMM: Y[b] = W (MxK, row-major) * X[b] (KxN, row-major)  (+ optional bias[M])
// 64x64 tile, K-tile 16, 256 threads, 4x4 per thread. OutT = float or bf16.
// ---------------------------------------------------------------------------
template <typename OutT>
__global__ __launch_bounds__(256) void gemm_f32k(
    const float* __restrict__ W, const float* __restrict__ X,
    OutT* __restrict__ Y, const float* __restrict__ bias,
    int M, int N, int K) {
  const int b = blockIdx.z;
  X += (size_t)b * K * N;
  Y += (size_t)b * M * N;

  __shared__ float As[16][64];   // [k][m]
  __shared__ float Bs[16][64];   // [k][n]

  const int t  = threadIdx.x;
  const int tx = t & 15;
  const int ty = t >> 4;
  const int row0 = blockIdx.y * 64;
  const int col0 = blockIdx.x * 64;

  float acc[4][4];
#pragma unroll
  for (int i = 0; i < 4; ++i)
#pragma unroll
    for (int j = 0; j < 4; ++j) acc[i][j] = 0.0f;

  for (int k0 = 0; k0 < K; k0 += 16) {
#pragma unroll
    for (int l = t; l < 64 * 16; l += 256) {
      int kk = l & 15, mm = l >> 4;
      As[kk][mm] = W[(size_t)(row0 + mm) * K + (k0 + kk)];
    }
#pragma unroll
    for (int l = t; l < 16 * 64; l += 256) {
      int nn = l & 63, kk = l >> 6;
      Bs[kk][nn] = X[(size_t)(k0 + kk) * N + (col0 + nn)];
    }
    __syncthreads();
#pragma unroll
    for (int kk = 0; kk < 16; ++kk) {
      float4 a  = *(const float4*)&As[kk][ty * 4];
      float4 bb = *(const float4*)&Bs[kk][tx * 4];
      float av[4] = {a.x, a.y, a.z, a.w};
      float bv[4] = {bb.x, bb.y, bb.z, bb.w};
#pragma unroll
      for (int i = 0; i < 4; ++i)
#pragma unroll
        for (int j = 0; j < 4; ++j) acc[i][j] = fmaf(av[i], bv[j], acc[i][j]);
    }
    __syncthreads();
  }

#pragma unroll
  for (int i = 0; i < 4; ++i) {
    int mm = row0 + ty * 4 + i;
    float bv = bias ? bias[mm] : 0.0f;
#pragma unroll
    for (int j = 0; j < 4; ++j) {
      float v = acc[i][j] + bv;
      if constexpr (std::is_same_v<OutT, float>)
        Y[(size_t)mm * N + col0 + tx * 4 + j] = v;
      else
        Y[(size_t)mm * N + col0 + tx * 4 + j] = __float2bfloat16(v);
    }
  }
}

// ---------------------------------------------------------------------------
// MFMA flash attention (bf16 inputs, fp32 softmax/accum).
// qkv bf16 [B][768][n]; q ch h*32+d, k ch 256+h*32+d, v ch 512+h*32+d.
// Block = (b, h, 64-query tile), 4 waves; wave wq owns queries wq*16..+15.
// Per 64-key strip: S = Q^T K via 4 mfma_16x16x32; online softmax in C/D
// layout (row=(l>>4)*4+r, col=l&15); P transposed via per-wave LDS; PV via
// 4 mfma. A/B fragments all loaded with the SAME assumed k-mapping
// (k = (lane>>4)*8 + e) so any HW k-permutation cancels between A and B.
// ---------------------------------------------------------------------------
__global__ __launch_bounds__(256) void attn_mfma(
    const __hip_bfloat16* __restrict__ qkv, float* __restrict__ out) {
  const int n  = NSP;
  const int it = blockIdx.x;
  const int h  = blockIdx.y;
  const int b  = blockIdx.z;
  const float scale = 0.17677669529663687f;  // 32^-0.5

  const __hip_bfloat16* qb = qkv + ((size_t)b * 768 + h * 32) * n;
  const __hip_bfloat16* kb = qb + (size_t)256 * n;
  const __hip_bfloat16* vb = qb + (size_t)512 * n;
  float* ob = out + ((size_t)b * 256 + h * 32) * n;

  __shared__ __align__(16) unsigned short Kt[64][40];       // K^T [j][d], pad 40
  __shared__ __align__(16) unsigned short Vs[32][72];       // V   [d][j], pad 72
  __shared__ __align__(16) unsigned short Ps[4][16][72];    // per-wave P [i][j]
  __shared__ __align__(16) union UQ { unsigned short q[32][72]; float o[32][68]; } U;

  const int t    = threadIdx.x;
  const int lane = t & 63;
  const int wq   = t >> 6;        // wave -> 16-query subtile
  const int lo   = lane & 15;
  const int g    = lane >> 4;
  const int i0   = it * 64;

  // ---- stage Q tile [32][64] (coalesced uint2 rows) ----
  for (int idx = t; idx < 32 * 16; idx += 256) {
    int d = idx >> 4, c = (idx & 15) * 4;
    *(uint2*)&U.q[d][c] = *(const uint2*)(qb + (size_t)d * n + i0 + c);
  }
  __syncthreads();

  // ---- Q fragment: A[i=lo][k=g*8+e] = Q[g*8+e][wq*16+lo] ----
  short8 qf;
#pragma unroll
  for (int e = 0; e < 8; ++e)
    qf[e] = (short)U.q[g * 8 + e][wq * 16 + lo];

  float mrow[4], lrow[4];
#pragma unroll
  for (int r = 0; r < 4; ++r) { mrow[r] = -1e30f; lrow[r] = 0.0f; }
  f32x4 acc0 = {0, 0, 0, 0}, acc1 = {0, 0, 0, 0};

  for (int j0 = 0; j0 < n; j0 += 64) {
    __syncthreads();  // previous strip's Kt/Vs reads complete
    // ---- stage K transposed: Kt[j][d] ----
    for (int idx = t; idx < 32 * 32; idx += 256) {
      int d = idx >> 5, jc = (idx & 31) * 2;
      unsigned int val = *(const unsigned int*)(kb + (size_t)d * n + j0 + jc);
      Kt[jc][d]     = (unsigned short)(val & 0xffffu);
      Kt[jc + 1][d] = (unsigned short)(val >> 16);
    }
    // ---- stage V natural: Vs[d][j] ----
    for (int idx = t; idx < 32 * 16; idx += 256) {
      int d = idx >> 4, c = (idx & 15) * 4;
      *(uint2*)&Vs[d][c] = *(const uint2*)(vb + (size_t)d * n + j0 + c);
    }
    __syncthreads();

    // ---- S = Q^T K : D[i=4g+r][j=jt*16+lo] ----
    f32x4 s[4];
#pragma unroll
    for (int jt = 0; jt < 4; ++jt) {
      short8 kf = *(const short8*)&Kt[jt * 16 + lo][g * 8];
      s[jt] = __builtin_amdgcn_mfma_f32_16x16x32_bf16(qf, kf,
                (f32x4){0, 0, 0, 0}, 0, 0, 0);
    }

    // ---- online softmax over the 64-key strip ----
#pragma unroll
    for (int r = 0; r < 4; ++r) {
      float v = fmaxf(fmaxf(s[0][r], s[1][r]), fmaxf(s[2][r], s[3][r]));
#pragma unroll
      for (int mask = 1; mask < 16; mask <<= 1)
        v = fmaxf(v, __shfl_xor(v, mask, 64));
      float mnew = fmaxf(mrow[r], v * scale);
      float corr = __expf(mrow[r] - mnew);
      mrow[r] = mnew;
      lrow[r] *= corr;
      acc0[r] *= corr;
      acc1[r] *= corr;
    }
    float psum[4] = {0, 0, 0, 0};
#pragma unroll
    for (int jt = 0; jt < 4; ++jt)
#pragma unroll
      for (int r = 0; r < 4; ++r) {
        float p = __expf(s[jt][r] * scale - mrow[r]);
        psum[r] += p;
        Ps[wq][g * 4 + r][jt * 16 + lo] = f2bf(p);
      }
#pragma unroll
    for (int r = 0; r < 4; ++r) {
      float v = psum[r];
#pragma unroll
      for (int mask = 1; mask < 16; mask <<= 1)
        v += __shfl_xor(v, mask, 64);
      lrow[r] += v;
    }

    // ---- PV: out[i][d] += P[i][j] V[d][j]  (contraction over 64 j) ----
#pragma unroll
    for (int jc = 0; jc < 2; ++jc) {
      short8 pf  = *(const short8*)&Ps[wq][lo][jc * 32 + g * 8];
      short8 vf0 = *(const short8*)&Vs[lo][jc * 32 + g * 8];
      short8 vf1 = *(const short8*)&Vs[16 + lo][jc * 32 + g * 8];
      acc0 = __builtin_amdgcn_mfma_f32_16x16x32_bf16(pf, vf0, acc0, 0, 0, 0);
      acc1 = __builtin_amdgcn_mfma_f32_16x16x32_bf16(pf, vf1, acc1, 0, 0, 0);
    }
  }

  // ---- epilogue: normalize, transpose via LDS, coalesced store ----
#pragma unroll
  for (int r = 0; r < 4; ++r) {
    float inv = 1.0f / lrow[r];
    U.o[lo][wq * 16 + g * 4 + r]      = acc0[r] * inv;
    U.o[16 + lo][wq * 16 + g * 4 + r] = acc1[r] * inv;
  }
  __syncthreads();
  for (int idx = t; idx < 32 * 64; idx += 256) {
    int d = idx >> 6, i = idx & 63;
    ob[(size_t)d * n + i0 + i] = U.o[d][i];
  }
}

// ---------------------------------------------------------------------------
extern "C" void kernel_launch(void* const* d_in, const int* in_sizes, int n_in,
                              void* d_out, int out_size, void* d_ws, size_t ws_size,
                              hipStream_t stream) {
  const float* x     = (const float*)d_in[0];  // [4][256][48][48]
  const float* w_qkv = (const float*)d_in[1];  // [768][256]
  const float* w_out = (const float*)d_in[2];  // [256][256]
  const float* b_out = (const float*)d_in[3];  // [256]
  float* out = (float*)d_out;                  // [4][256][48][48]

  __hip_bfloat16* qkv = (__hip_bfloat16*)d_ws;            // [4][768][2304] bf16
  float* attno = (float*)(qkv + (size_t)NB * 768 * NSP);  // [4][256][2304] f32

  dim3 blk(256);
  // QKV projection -> bf16
  gemm_f32k<__hip_bfloat16><<<dim3(NSP / 64, 768 / 64, NB), blk, 0, stream>>>(
      w_qkv, x, qkv, nullptr, 768, NSP, 256);
  // MFMA flash attention -> fp32
  attn_mfma<<<dim3(NSP / 64, 8, NB), blk, 0, stream>>>(qkv, attno);
  // Output projection + bias (fp32)
  gemm_f32k<float><<<dim3(NSP / 64, 256 / 64, NB), blk, 0, stream>>>(
      w_out, attno, out, b_out, 256, NSP, 256);
}

// Round 4
// 97.682 us; speedup vs baseline: 8.3631x; 2.9416x over previous
//
#include <hip/hip_runtime.h>
#include <hip/hip_bf16.h>

#define NSP 2304   // 48*48 spatial
#define NB  4      // batch

typedef unsigned short u16;
typedef __attribute__((ext_vector_type(8))) short short8;
typedef __attribute__((ext_vector_type(4))) float f32x4;
typedef __attribute__((ext_vector_type(4))) unsigned short u16x4;

static __device__ inline u16 f2bf(float f) {
  return __builtin_bit_cast(unsigned short, __float2bfloat16(f));
}

// ---------------------------------------------------------------------------
// prep 1: convert w_qkv (768*256) and w_out (256*256) fp32 -> bf16 into one
// contiguous region (wbf). 256 blocks * 256 thr * 4 elems.
// ---------------------------------------------------------------------------
__global__ __launch_bounds__(256) void convert_w(
    const float* __restrict__ wq, const float* __restrict__ wo,
    u16* __restrict__ dst) {
  int i = (blockIdx.x * 256 + threadIdx.x) * 4;
  float4 v;
  if (i < 196608) v = *(const float4*)(wq + i);
  else            v = *(const float4*)(wo + (i - 196608));
  u16x4 p = {f2bf(v.x), f2bf(v.y), f2bf(v.z), f2bf(v.w)};
  *(u16x4*)(dst + i) = p;
}

// ---------------------------------------------------------------------------
// prep 2: x fp32 [b][256][2304] -> xT bf16 [b][2304][256]
// 32x32 tiles via LDS. grid (72, 8, 4).
// ---------------------------------------------------------------------------
__global__ __launch_bounds__(256) void transpose_x(
    const float* __restrict__ x, u16* __restrict__ xT) {
  __shared__ float tile[32][33];
  const int t = threadIdx.x;
  const int n0 = blockIdx.x * 32, c0 = blockIdx.y * 32, b = blockIdx.z;
  const float* xb = x + ((size_t)b * 256 + c0) * NSP + n0;
#pragma unroll
  for (int e = t; e < 1024; e += 256) {
    int cc = e >> 5, nn = e & 31;
    tile[cc][nn] = xb[(size_t)cc * NSP + nn];
  }
  __syncthreads();
  u16* xTb = xT + ((size_t)b * NSP + n0) * 256 + c0;
#pragma unroll
  for (int e = t; e < 1024; e += 256) {
    int nn = e >> 5, cc = e & 31;
    xTb[(size_t)nn * 256 + cc] = f2bf(tile[cc][nn]);
  }
}

// ---------------------------------------------------------------------------
// bf16 MFMA GEMM: D = A (M x 256) * B[b] (N x 256)^T, 64x64 tile, 4 waves
// (2x2 of 32x32), whole K=256 staged once. Both operands [row][k] bf16 b128.
// EPI 0 (QKV): rows < 512 (q,k) -> qkT[b][n][512] transposed bf16 (b64 packs);
//              rows >= 512 (v)  -> vbuf[b][256][2304] natural bf16.
// EPI 1 (OUT): fp32 out[b][256][2304] + bias.
// ---------------------------------------------------------------------------
template <int EPI>
__global__ __launch_bounds__(256) void gemm_mfma(
    const u16* __restrict__ A, const u16* __restrict__ B,
    u16* __restrict__ qkT, u16* __restrict__ vbuf,
    float* __restrict__ outf, const float* __restrict__ bias, int N) {
  __shared__ u16 As[64][264];
  __shared__ u16 Bs[64][264];
  const int t = threadIdx.x, lane = t & 63, wid = t >> 6;
  const int lo = lane & 15, g = lane >> 4;
  const int wr = wid >> 1, wc = wid & 1;
  const int row0 = blockIdx.y * 64, col0 = blockIdx.x * 64, b = blockIdx.z;

  // ---- stage A(64x256) and B(64x256) as b128s ----
  const int sr = t >> 2, c4 = t & 3;
  const u16* Arow = A + (size_t)(row0 + sr) * 256;
  const u16* Brow = B + ((size_t)b * N + col0 + sr) * 256;
#pragma unroll
  for (int i = 0; i < 8; ++i) {
    int col = (c4 + 4 * i) * 8;
    *(uint4*)&As[sr][col] = *(const uint4*)&Arow[col];
    *(uint4*)&Bs[sr][col] = *(const uint4*)&Brow[col];
  }
  __syncthreads();

  f32x4 acc[2][2];
#pragma unroll
  for (int i = 0; i < 2; ++i)
#pragma unroll
    for (int j = 0; j < 2; ++j) acc[i][j] = (f32x4){0, 0, 0, 0};

  const int ar0 = wr * 32 + lo, br0 = wc * 32 + lo;
#pragma unroll
  for (int kk = 0; kk < 8; ++kk) {
    int kc = kk * 32 + g * 8;
    short8 a0 = *(const short8*)&As[ar0][kc];
    short8 a1 = *(const short8*)&As[ar0 + 16][kc];
    short8 b0 = *(const short8*)&Bs[br0][kc];
    short8 b1 = *(const short8*)&Bs[br0 + 16][kc];
    acc[0][0] = __builtin_amdgcn_mfma_f32_16x16x32_bf16(a0, b0, acc[0][0], 0, 0, 0);
    acc[0][1] = __builtin_amdgcn_mfma_f32_16x16x32_bf16(a0, b1, acc[0][1], 0, 0, 0);
    acc[1][0] = __builtin_amdgcn_mfma_f32_16x16x32_bf16(a1, b0, acc[1][0], 0, 0, 0);
    acc[1][1] = __builtin_amdgcn_mfma_f32_16x16x32_bf16(a1, b1, acc[1][1], 0, 0, 0);
  }

  // ---- epilogue. D row = row0+wr*32+m2*16+g*4+r, col = col0+wc*32+n2*16+lo.
#pragma unroll
  for (int m2 = 0; m2 < 2; ++m2)
#pragma unroll
    for (int n2 = 0; n2 < 2; ++n2) {
      int m = row0 + wr * 32 + m2 * 16 + g * 4;
      int n = col0 + wc * 32 + n2 * 16 + lo;
      if constexpr (EPI == 0) {
        if (row0 < 512) {  // q,k -> transposed qkT[b][n][m..m+3]
          u16x4 pk = {f2bf(acc[m2][n2][0]), f2bf(acc[m2][n2][1]),
                      f2bf(acc[m2][n2][2]), f2bf(acc[m2][n2][3])};
          *(u16x4*)(qkT + ((size_t)b * NSP + n) * 512 + m) = pk;
        } else {           // v -> natural vbuf[b][m-512][n]
#pragma unroll
          for (int r = 0; r < 4; ++r)
            vbuf[((size_t)b * 256 + (m - 512 + r)) * NSP + n] =
                f2bf(acc[m2][n2][r]);
        }
      } else {
#pragma unroll
        for (int r = 0; r < 4; ++r)
          outf[((size_t)b * 256 + m + r) * NSP + n] =
              acc[m2][n2][r] + bias[m + r];
      }
    }
}

// ---------------------------------------------------------------------------
// MFMA flash attention, no-max softmax (fixed offset 12), 1 barrier/strip.
// Inputs: qkT[b][n][512] (q at col h*32+d, k at col 256+h*32+d),
//         vbuf[b][256][2304]. Output attnoT[b][n][256] bf16.
// Block = (64-query tile, h, b), 4 waves; wave wq owns queries wq*16..+15.
// Per 64-key strip: 4 S-mfma, 16 exp2, 4 PV-mfma; K/V double-buffered with
// reg-staged prefetch; lsum reduced once at the end.
// ---------------------------------------------------------------------------
__global__ __launch_bounds__(256) void attn_mfma(
    const u16* __restrict__ qkT, const u16* __restrict__ vbuf,
    u16* __restrict__ attnoT) {
  const int it = blockIdx.x, h = blockIdx.y, b = blockIdx.z;
  const int t = threadIdx.x, lane = t & 63, wq = t >> 6;
  const int lo = lane & 15, g = lane >> 4;
  const int i0 = it * 64;
  const float k1 = 0.25508040852656425f;   // 32^-0.5 * log2(e)
  const float k2 = -17.312340490667562f;   // -12 * log2(e)

  const u16* qkTb = qkT + (size_t)b * NSP * 512;
  const u16* vb   = vbuf + ((size_t)b * 256 + h * 32) * NSP;
  u16* ob = attnoT + ((size_t)b * NSP + i0) * 256 + h * 32;

  __shared__ u16 Kt[2][64][40];   // [j][d], stride 40 -> frag reads conflict-free
  __shared__ u16 Vs[2][32][72];   // [d][j]
  __shared__ u16 Ps[4][16][72];   // per-wave P [query][key]

  // Q fragment straight from global (qkT row = query, cols contiguous in d)
  short8 qf = *(const short8*)(qkTb + (size_t)(i0 + wq * 16 + lo) * 512 +
                               h * 32 + g * 8);

  // staging addresses (one b128 per thread per buffer)
  const int kr = t >> 2, kp = (t & 3) * 8;   // K: row j (64), d-part
  const int vr = t >> 3, vp = (t & 7) * 8;   // V: row d (32), j-part
  const u16* ksrc = qkTb + 256 + h * 32 + kp;           // + j*512
  const u16* vsrc = vb + (size_t)vr * NSP + vp;         // + j0

  uint4 kreg = *(const uint4*)(ksrc + (size_t)kr * 512);
  uint4 vreg = *(const uint4*)(vsrc);
  *(uint4*)&Kt[0][kr][kp] = kreg;
  *(uint4*)&Vs[0][vr][vp] = vreg;
  __syncthreads();

  float psum[4] = {0, 0, 0, 0};
  f32x4 acc0 = {0, 0, 0, 0}, acc1 = {0, 0, 0, 0};

  for (int s = 0; s < 36; ++s) {
    const int cur = s & 1;
    if (s + 1 < 36) {  // issue next strip's loads early (hide under compute)
      int j0n = (s + 1) * 64;
      kreg = *(const uint4*)(ksrc + (size_t)(j0n + kr) * 512);
      vreg = *(const uint4*)(vsrc + j0n);
    }

    // ---- S = Q K^T ----
    f32x4 sv[4];
#pragma unroll
    for (int jt = 0; jt < 4; ++jt) {
      short8 kf = *(const short8*)&Kt[cur][jt * 16 + lo][g * 8];
      sv[jt] = __builtin_amdgcn_mfma_f32_16x16x32_bf16(
          qf, kf, (f32x4){0, 0, 0, 0}, 0, 0, 0);
    }

    // ---- softmax numerator, fixed offset (no max tracking) ----
#pragma unroll
    for (int jt = 0; jt < 4; ++jt)
#pragma unroll
      for (int r = 0; r < 4; ++r) {
        float p = __builtin_amdgcn_exp2f(fmaf(sv[jt][r], k1, k2));
        psum[r] += p;
        Ps[wq][g * 4 + r][jt * 16 + lo] = f2bf(p);
      }

    // ---- PV ----
#pragma unroll
    for (int jc = 0; jc < 2; ++jc) {
      short8 pf  = *(const short8*)&Ps[wq][lo][jc * 32 + g * 8];
      short8 vf0 = *(const short8*)&Vs[cur][lo][jc * 32 + g * 8];
      short8 vf1 = *(const short8*)&Vs[cur][16 + lo][jc * 32 + g * 8];
      acc0 = __builtin_amdgcn_mfma_f32_16x16x32_bf16(pf, vf0, acc0, 0, 0, 0);
      acc1 = __builtin_amdgcn_mfma_f32_16x16x32_bf16(pf, vf1, acc1, 0, 0, 0);
    }

    if (s + 1 < 36) {  // write next strip into the other buffer
      *(uint4*)&Kt[cur ^ 1][kr][kp] = kreg;
      *(uint4*)&Vs[cur ^ 1][vr][vp] = vreg;
    }
    __syncthreads();
  }

  // ---- lsum reduce (once) + normalized bf16 store to attnoT[n][c] ----
#pragma unroll
  for (int r = 0; r < 4; ++r) {
    float v = psum[r];
#pragma unroll
    for (int m = 1; m < 16; m <<= 1) v += __shfl_xor(v, m, 64);
    float inv = 1.0f / v;
    int row = wq * 16 + g * 4 + r;
    ob[(size_t)row * 256 + lo]      = f2bf(acc0[r] * inv);
    ob[(size_t)row * 256 + 16 + lo] = f2bf(acc1[r] * inv);
  }
}

// ---------------------------------------------------------------------------
extern "C" void kernel_launch(void* const* d_in, const int* in_sizes, int n_in,
                              void* d_out, int out_size, void* d_ws, size_t ws_size,
                              hipStream_t stream) {
  const float* x     = (const float*)d_in[0];  // [4][256][48][48]
  const float* w_qkv = (const float*)d_in[1];  // [768][256]
  const float* w_out = (const float*)d_in[2];  // [256][256]
  const float* b_out = (const float*)d_in[3];  // [256]
  float* out = (float*)d_out;                  // [4][256][2304]

  u16* wbf    = (u16*)d_ws;                    // wqkv 196608 then wout 65536
  u16* xT     = wbf + 262144;                  // [4][2304][256]
  u16* qkT    = xT + (size_t)NB * NSP * 256;   // [4][2304][512]
  u16* vbuf   = qkT + (size_t)NB * NSP * 512;  // [4][256][2304]
  u16* attnoT = vbuf + (size_t)NB * 256 * NSP; // [4][2304][256]

  dim3 blk(256);
  convert_w<<<256, blk, 0, stream>>>(w_qkv, w_out, wbf);
  transpose_x<<<dim3(NSP / 32, 8, NB), blk, 0, stream>>>(x, xT);
  // QKV projection (A = wqkv bf16, B = xT rows): writes qkT + vbuf
  gemm_mfma<0><<<dim3(NSP / 64, 12, NB), blk, 0, stream>>>(
      wbf, xT, qkT, vbuf, nullptr, nullptr, NSP);
  // attention
  attn_mfma<<<dim3(NSP / 64, 8, NB), blk, 0, stream>>>(qkT, vbuf, attnoT);
  // output projection + bias (A = wout bf16, B = attnoT rows) -> fp32 out
  gemm_mfma<1><<<dim3(NSP / 64, 4, NB), blk, 0, stream>>>(
      wbf + 196608, attnoT, nullptr, nullptr, out, b_out, NSP);
}